// Round 6
// baseline (433.847 us; speedup 1.0000x reference)
//
#include <hip/hip_runtime.h>
#include <hip/hip_cooperative_groups.h>
#include <math.h>

// EMA along T: y[0]=x[0]; y[t] = (1-a)*y[t-1] + a*x[t], a=0.01.
//
// FUSED cooperative kernel: phase A (per-chunk local EMA end-states) and
// phase B (bounded-lookback carry fold + apply) in ONE dispatch separated
// by grid.sync(). Rationale (R0..R5 evidence): four different 2-kernel
// variants all land 250-262us while BW arithmetic says the kernels cost
// ~50us -> the slack is dispatch boundaries, not kernel internals. Fusing
// deletes one full drain+launch and makes the kernel big enough to surface
// in rocprof top-5 for real per-kernel counters.
//
// Correctness notes:
//  - Cross-XCD visibility of 'ends' across grid.sync(): release fence
//    (threadfence -> L2 writeback) before barrier, acquire after; proven
//    correct on this chip by R3's fused kernel (slow but never wrong).
//  - Co-residency for cooperative launch: 1024 blocks x 128 thr, 0 LDS,
//    low VGPR -> >=8 blocks/CU capacity vs 4 needed. If the cooperative
//    launch is rejected we fall back to the proven 2-kernel path (R2).
//  - Lookback W=16 chunks = 1024 steps: truncation 0.99^1024*|S|max ~1e-5,
//    ~300x below accepted absmax; EXACT for k<=W (ends[0] = true S_0 via
//    the y_pre=x[0] init trick).
//  - R3 counters proved the phase-B x re-read L3-hits (FETCH 139MB for a
//    2x-reader) and NT out-stores keep x L3-resident.

namespace cg = cooperative_groups;

namespace {
constexpr int B = 8;
constexpr int T = 8192;
constexpr int C = 512;
constexpr float ALPHA = 0.01f;
constexpr float DECAY = 1.0f - ALPHA;   // 0.99
constexpr int S4 = C / 4;               // float4 per timestep = 128
constexpr int TPB = S4;                 // 128 threads, 4 channels each
constexpr int CHUNK = 64;               // timesteps per block
constexpr int K = T / CHUNK;            // 128 chunks -> grid (128,8) = 1024 blocks
constexpr int W = 16;                   // lookback chunks (1024 steps)

typedef float f32x4 __attribute__((ext_vector_type(4)));

// 0.99^n folded at compile time (float, matches device math).
constexpr float dpow(int n) {
    float r = 1.0f;
    for (int i = 0; i < n; ++i) r *= DECAY;
    return r;
}

__device__ __forceinline__ void ema_step(float4& y, const float4 v) {
    y.x = DECAY * y.x + ALPHA * v.x;
    y.y = DECAY * y.y + ALPHA * v.y;
    y.z = DECAY * y.z + ALPHA * v.z;
    y.w = DECAY * y.w + ALPHA * v.w;
}

__device__ __forceinline__ void wsum(float4& a, const float w, const float4 v) {
    a.x += w * v.x;
    a.y += w * v.y;
    a.z += w * v.z;
    a.w += w * v.w;
}
}

__global__ __launch_bounds__(TPB) void ema_fused(const float* __restrict__ x,
                                                 float* __restrict__ out,
                                                 float* __restrict__ ends) {
    const int k = blockIdx.x;
    const int b = blockIdx.y;
    const int tid = threadIdx.x;
    const size_t base4 = (size_t)(b * T + k * CHUNK) * S4 + tid;
    const float4* xp = reinterpret_cast<const float4*>(x) + base4;
    float4* ep = reinterpret_cast<float4*>(ends) + (size_t)b * K * S4 + tid;

    // ---- Phase A: per-chunk local EMA end-state (serial chain, unroll 8;
    // low-VGPR, proven adequate in R2). k==0 uses the true-init trick.
    float4 y;
    if (k == 0) {
        y = xp[0];
    } else {
        y = make_float4(0.f, 0.f, 0.f, 0.f);
    }
#pragma unroll 8
    for (int t = 0; t < CHUNK; ++t) {
        float4 v = xp[(size_t)t * S4];
        ema_step(y, v);
    }
    ep[(size_t)k * S4] = y;

    // Release 'ends' device-wide, then grid barrier.
    __threadfence();
    cg::this_grid().sync();
    __threadfence();

    // ---- Phase B: carry-in via bounded lookback, then apply.
    if (k == 0) {
        y = xp[0];  // true init again for the apply pass
    } else if (k > W) {
        // carry = sum_{j=0}^{W-1} (0.99^CHUNK)^j * E_{k-1-j}; weighted sum,
        // 4 independent accumulators (absmax-validated in R5).
        float4 c0 = make_float4(0.f, 0.f, 0.f, 0.f);
        float4 c1 = c0, c2 = c0, c3 = c0;
#pragma unroll
        for (int j = 0; j < W; j += 4) {
            float4 e0 = ep[(size_t)(k - 1 - (j + 0)) * S4];
            float4 e1 = ep[(size_t)(k - 1 - (j + 1)) * S4];
            float4 e2 = ep[(size_t)(k - 1 - (j + 2)) * S4];
            float4 e3 = ep[(size_t)(k - 1 - (j + 3)) * S4];
            wsum(c0, dpow(CHUNK * (j + 0)), e0);
            wsum(c1, dpow(CHUNK * (j + 1)), e1);
            wsum(c2, dpow(CHUNK * (j + 2)), e2);
            wsum(c3, dpow(CHUNK * (j + 3)), e3);
        }
        y.x = (c0.x + c1.x) + (c2.x + c3.x);
        y.y = (c0.y + c1.y) + (c2.y + c3.y);
        y.z = (c0.z + c1.z) + (c2.z + c3.z);
        y.w = (c0.w + c1.w) + (c2.w + c3.w);
    } else {
        // 1 <= k <= W: exact sequential fold from E_0 (= true S_0).
        constexpr float dC = dpow(CHUNK);
        y = make_float4(0.f, 0.f, 0.f, 0.f);
        for (int m = 0; m < k; ++m) {
            float4 e = ep[(size_t)m * S4];
            y.x = dC * y.x + e.x;
            y.y = dC * y.y + e.y;
            y.z = dC * y.z + e.z;
            y.w = dC * y.w + e.w;
        }
    }

    // Apply: true recurrence, unroll 8; x re-read L3-hits; NT out-stores.
    float4* op = reinterpret_cast<float4*>(out) + base4;
#pragma unroll 8
    for (int t = 0; t < CHUNK; ++t) {
        float4 v = xp[(size_t)t * S4];
        ema_step(y, v);
        __builtin_nontemporal_store(*reinterpret_cast<const f32x4*>(&y),
                                    reinterpret_cast<f32x4*>(op + (size_t)t * S4));
    }
}

// ---- Fallback path (R2-proven 2-kernel structure) ----

__global__ __launch_bounds__(TPB) void ema_ends(const float* __restrict__ x,
                                                float* __restrict__ ends) {
    const int k = blockIdx.x;
    const int b = blockIdx.y;
    const int tid = threadIdx.x;
    const float4* xp = reinterpret_cast<const float4*>(x) +
                       (size_t)(b * T + k * CHUNK) * S4 + tid;
    float4 y;
    if (k == 0) {
        y = xp[0];
    } else {
        y = make_float4(0.f, 0.f, 0.f, 0.f);
    }
#pragma unroll 8
    for (int t = 0; t < CHUNK; ++t) {
        float4 v = xp[(size_t)t * S4];
        ema_step(y, v);
    }
    reinterpret_cast<float4*>(ends)[(size_t)(b * K + k) * S4 + tid] = y;
}

__global__ __launch_bounds__(TPB) void ema_apply(const float* __restrict__ x,
                                                 const float* __restrict__ ends,
                                                 float* __restrict__ out) {
    const int k = blockIdx.x;
    const int b = blockIdx.y;
    const int tid = threadIdx.x;
    const size_t base4 = (size_t)(b * T + k * CHUNK) * S4 + tid;
    const float4* xp = reinterpret_cast<const float4*>(x) + base4;
    float4* op = reinterpret_cast<float4*>(out) + base4;
    const float4* ep = reinterpret_cast<const float4*>(ends) +
                       (size_t)b * K * S4 + tid;
    float4 y;
    if (k == 0) {
        y = xp[0];
    } else if (k > W) {
        float4 c0 = make_float4(0.f, 0.f, 0.f, 0.f);
        float4 c1 = c0, c2 = c0, c3 = c0;
#pragma unroll
        for (int j = 0; j < W; j += 4) {
            float4 e0 = ep[(size_t)(k - 1 - (j + 0)) * S4];
            float4 e1 = ep[(size_t)(k - 1 - (j + 1)) * S4];
            float4 e2 = ep[(size_t)(k - 1 - (j + 2)) * S4];
            float4 e3 = ep[(size_t)(k - 1 - (j + 3)) * S4];
            wsum(c0, dpow(CHUNK * (j + 0)), e0);
            wsum(c1, dpow(CHUNK * (j + 1)), e1);
            wsum(c2, dpow(CHUNK * (j + 2)), e2);
            wsum(c3, dpow(CHUNK * (j + 3)), e3);
        }
        y.x = (c0.x + c1.x) + (c2.x + c3.x);
        y.y = (c0.y + c1.y) + (c2.y + c3.y);
        y.z = (c0.z + c1.z) + (c2.z + c3.z);
        y.w = (c0.w + c1.w) + (c2.w + c3.w);
    } else {
        constexpr float dC = dpow(CHUNK);
        y = make_float4(0.f, 0.f, 0.f, 0.f);
        for (int m = 0; m < k; ++m) {
            float4 e = ep[(size_t)m * S4];
            y.x = dC * y.x + e.x;
            y.y = dC * y.y + e.y;
            y.z = dC * y.z + e.z;
            y.w = dC * y.w + e.w;
        }
    }
#pragma unroll 8
    for (int t = 0; t < CHUNK; ++t) {
        float4 v = xp[(size_t)t * S4];
        ema_step(y, v);
        __builtin_nontemporal_store(*reinterpret_cast<const f32x4*>(&y),
                                    reinterpret_cast<f32x4*>(op + (size_t)t * S4));
    }
}

// Exact but slow fallback if ws is too small (one block per batch).
__global__ __launch_bounds__(TPB) void ema_seq_kernel(const float* __restrict__ x,
                                                      float* __restrict__ out) {
    const int b = blockIdx.x;
    const int tid = threadIdx.x;
    const float4* xp = reinterpret_cast<const float4*>(x) + (size_t)b * T * S4 + tid;
    float4* op = reinterpret_cast<float4*>(out) + (size_t)b * T * S4 + tid;
    float4 y = xp[0];
    for (int t = 0; t < T; ++t) {
        float4 v = xp[(size_t)t * S4];
        ema_step(y, v);
        op[(size_t)t * S4] = y;
    }
}

extern "C" void kernel_launch(void* const* d_in, const int* in_sizes, int n_in,
                              void* d_out, int out_size, void* d_ws, size_t ws_size,
                              hipStream_t stream) {
    (void)in_sizes; (void)n_in; (void)out_size;
    const float* x = reinterpret_cast<const float*>(d_in[0]);
    float* out = reinterpret_cast<float*>(d_out);

    const size_t need = (size_t)B * K * C * sizeof(float);  // 2 MB
    if (ws_size >= need) {
        float* ends = reinterpret_cast<float*>(d_ws);
        void* args[] = {(void*)&x, (void*)&out, (void*)&ends};
        hipError_t err = hipLaunchCooperativeKernel(
            reinterpret_cast<const void*>(ema_fused),
            dim3(K, B), dim3(TPB), args, 0, stream);
        if (err != hipSuccess) {
            // Cooperative launch rejected (capacity/capture) -> proven 2-kernel path.
            ema_ends<<<dim3(K, B), dim3(TPB), 0, stream>>>(x, ends);
            ema_apply<<<dim3(K, B), dim3(TPB), 0, stream>>>(x, ends, out);
        }
    } else {
        ema_seq_kernel<<<dim3(B), dim3(TPB), 0, stream>>>(x, out);
    }
}

// Round 7
// 250.829 us; speedup vs baseline: 1.7297x; 1.7297x over previous
//
#include <hip/hip_runtime.h>
#include <math.h>

// EMA along T: y[0]=x[0]; y[t] = (1-a)*y[t-1] + a*x[t], a=0.01.
//
// EXACT revert to the round-2 kernel (measured best: 250.8us). Session
// evidence for why this structure is final:
//  - R3/R6 (measured twice): any single-dispatch scheme needing device-scope
//    visibility mid-kernel (spin-flags or grid.sync) pays ~200us: agent-scope
//    release/acquire on 8 non-coherent per-XCD L2s = L2 writeback + L2/L1
//    invalidate, after which all reads run latency-bound at ~1 TB/s.
//    The dispatch boundary IS the cheapest device-wide barrier on this chip.
//  - R4 (waves/CU 8->16), R5 (weighted-sum ILP, W=16, reg double-buffer):
//    all within noise or worse -> the slice is not occupancy- or ILP-bound.
//  - R3/R6 FETCH=139MB for 2x-readers: phase-2's x re-read L3-hits and NT
//    out-stores keep x resident -> HBM traffic already at ~256MB floor.
//
// Structure: 2-phase chunked scan exploiting EMA forgetting. Carry-in uses
// a bounded W=32-chunk lookback (2048 steps; truncation 0.99^2048 ~ 1.2e-9,
// far below accepted absmax; EXACT for k<=W since ends[0] holds true S_0).

namespace {
constexpr int B = 8;
constexpr int T = 8192;
constexpr int C = 512;
constexpr float ALPHA = 0.01f;
constexpr float DECAY = 1.0f - ALPHA;   // 0.99
constexpr int S4 = C / 4;               // float4 per timestep = 128
constexpr int TPB = S4;                 // 128 threads, 4 channels each
constexpr int CHUNK = 64;               // timesteps per block
constexpr int K = T / CHUNK;            // 128 chunks -> grid (128,8)
constexpr int W = 32;                   // carry lookback in chunks

typedef float f32x4 __attribute__((ext_vector_type(4)));

__device__ __forceinline__ void ema_step(float4& y, const float4 v) {
    y.x = DECAY * y.x + ALPHA * v.x;
    y.y = DECAY * y.y + ALPHA * v.y;
    y.z = DECAY * y.z + ALPHA * v.z;
    y.w = DECAY * y.w + ALPHA * v.w;
}
}

// Phase 1: per-chunk local EMA end-state. k==0 starts from the true init
// (y_pre = x[0] => y[0] = x[0]), so ends[0] holds the TRUE running state
// S_0; k>0 chunks start from 0 and produce local sums L_k.
__global__ __launch_bounds__(TPB) void ema_ends(const float* __restrict__ x,
                                                float* __restrict__ ends) {
    const int k = blockIdx.x;
    const int b = blockIdx.y;
    const int tid = threadIdx.x;
    const float4* xp = reinterpret_cast<const float4*>(x) +
                       (size_t)(b * T + k * CHUNK) * S4 + tid;
    float4 y;
    if (k == 0) {
        y = xp[0];
    } else {
        y = make_float4(0.f, 0.f, 0.f, 0.f);
    }
#pragma unroll 8
    for (int t = 0; t < CHUNK; ++t) {
        float4 v = xp[(size_t)t * S4];
        ema_step(y, v);
    }
    reinterpret_cast<float4*>(ends)[(size_t)(b * K + k) * S4 + tid] = y;
}

// Phase 2: carry fold (bounded window) + apply.
// Exact carry: S_{k-1} = sum_{m=0}^{k-1} dC^{k-1-m} E_m  (E_0 = S_0 true).
// We keep only m >= k-W; dropped mass = dC^W * S_{k-W-1} ~ 6e-10. For k <= W
// the fold is EXACT (reaches m=0). Fold: 32 independent L2 loads feeding a
// 32-step FMA chain — uniform across blocks, no serialization.
__global__ __launch_bounds__(TPB) void ema_fold_apply(const float* __restrict__ x,
                                                      const float* __restrict__ ends,
                                                      float* __restrict__ out,
                                                      float dC) {
    const int k = blockIdx.x;
    const int b = blockIdx.y;
    const int tid = threadIdx.x;
    const size_t base4 = (size_t)(b * T + k * CHUNK) * S4 + tid;
    const float4* xp = reinterpret_cast<const float4*>(x) + base4;
    float4* op = reinterpret_cast<float4*>(out) + base4;

    float4 y;
    if (k == 0) {
        y = xp[0];  // true init trick (see phase 1)
    } else {
        y = make_float4(0.f, 0.f, 0.f, 0.f);
        const float4* ep = reinterpret_cast<const float4*>(ends) +
                           (size_t)b * K * S4 + tid;
        int m0 = k - W;
        if (m0 < 0) m0 = 0;
#pragma unroll 8
        for (int m = m0; m < k; ++m) {
            float4 e = ep[(size_t)m * S4];
            y.x = dC * y.x + e.x;
            y.y = dC * y.y + e.y;
            y.z = dC * y.z + e.z;
            y.w = dC * y.w + e.w;
        }
    }
#pragma unroll 8
    for (int t = 0; t < CHUNK; ++t) {
        float4 v = xp[(size_t)t * S4];
        ema_step(y, v);
        // NT store: out is never re-read; keep x resident in L3 for this
        // kernel's own read stream (verified R3/R6: FETCH 139MB).
        __builtin_nontemporal_store(*reinterpret_cast<const f32x4*>(&y),
                                    reinterpret_cast<f32x4*>(op + (size_t)t * S4));
    }
}

// Exact but slow fallback if ws is too small (one block per batch).
__global__ __launch_bounds__(TPB) void ema_seq_kernel(const float* __restrict__ x,
                                                      float* __restrict__ out) {
    const int b = blockIdx.x;
    const int tid = threadIdx.x;
    const float4* xp = reinterpret_cast<const float4*>(x) + (size_t)b * T * S4 + tid;
    float4* op = reinterpret_cast<float4*>(out) + (size_t)b * T * S4 + tid;
    float4 y = xp[0];
    for (int t = 0; t < T; ++t) {
        float4 v = xp[(size_t)t * S4];
        ema_step(y, v);
        op[(size_t)t * S4] = y;
    }
}

extern "C" void kernel_launch(void* const* d_in, const int* in_sizes, int n_in,
                              void* d_out, int out_size, void* d_ws, size_t ws_size,
                              hipStream_t stream) {
    (void)in_sizes; (void)n_in; (void)out_size;
    const float* x = reinterpret_cast<const float*>(d_in[0]);
    float* out = reinterpret_cast<float*>(d_out);

    const size_t need = (size_t)B * K * C * sizeof(float);  // 2 MB
    if (ws_size >= need) {
        float* ends = reinterpret_cast<float*>(d_ws);
        const float dC = (float)pow((double)DECAY, (double)CHUNK);
        ema_ends<<<dim3(K, B), dim3(TPB), 0, stream>>>(x, ends);
        ema_fold_apply<<<dim3(K, B), dim3(TPB), 0, stream>>>(x, ends, out, dC);
    } else {
        ema_seq_kernel<<<dim3(B), dim3(TPB), 0, stream>>>(x, out);
    }
}